// Round 6
// baseline (88.340 us; speedup 1.0000x reference)
//
#include <hip/hip_runtime.h>

typedef _Float16 half8 __attribute__((ext_vector_type(8)));
typedef _Float16 half4 __attribute__((ext_vector_type(4)));
typedef float    f32x4 __attribute__((ext_vector_type(4)));

// ws layout (halves), FRAGMENT-ORDERED for conflict-free ds_read_b128:
//   L1: frag f = nb*2 + vkb   (nb 0..7)          halves [0, 8192)
//   L2: frag f = nb*4 + kb    (nb 0..7, kb 0..3)  halves [8192, 24576)
//   L3: frag f = kb           (kb 0..3)           halves [24576, 26624)
//   wh[base + (f*64 + lane)*8 + j] = W[n = f_n*16 + (lane&15)][k = f_k*32 + (lane>>4)*8 + j]
#define WH_HALVES      26624
#define ALPHA_BYTE_OFF 53248

#define NBLOCKS  256
#define ITERS    9           // 2304 tiles of 4x64 px

__global__ __launch_bounds__(256) void prep_weights(
    const float* __restrict__ w1, const float* __restrict__ w2,
    const float* __restrict__ w3, _Float16* __restrict__ wh)
{
    int i = blockIdx.x * 256 + threadIdx.x;
    if (i >= WH_HALVES) return;
    int rem = i & 511;
    int l = rem >> 3, j = rem & 7;
    int lr = l & 15, lg = l >> 4;
    _Float16 v;
    if (i < 8192) {                       // L1: K padded 48->64
        int f = i >> 9;
        int nb = f >> 1, hh = f & 1;
        int o = nb * 16 + lr, k = hh * 32 + lg * 8 + j;
        v = (k < 48) ? (_Float16)w1[o * 48 + k] : (_Float16)0.f;
    } else if (i < 24576) {               // L2
        int f = (i - 8192) >> 9;
        int nb = f >> 2, kb = f & 3;
        v = (_Float16)w2[(nb * 16 + lr) * 128 + kb * 32 + lg * 8 + j];
    } else {                              // L3
        int kb = (i - 24576) >> 9;
        v = (_Float16)w3[lr * 128 + kb * 32 + lg * 8 + j];
    }
    wh[i] = v;
}

// halo staging units: (row 0..5, col 0..65, cq 0..3) -> 1584 b64 writes
#define HALO_UNITS 1584

__device__ __forceinline__ void halo_loads(const float* __restrict__ x,
                                           int bb, int h0, int w0, int tid,
                                           float pfv[4][4])
{
#pragma unroll
    for (int k = 0; k < 4; ++k) {
        int u = tid + k * 512;
        bool valid = (u < HALO_UNITS);
        int uu = valid ? u : 0;
        int row = uu / 264, rem = uu % 264;
        int col = rem >> 2, cq = rem & 3;
        int hh = h0 - 1 + row, ww = w0 - 1 + col;
        bool inb = valid && hh >= 0 && hh < 192 && ww >= 0 && ww < 192;
#pragma unroll
        for (int cc = 0; cc < 4; ++cc)
            pfv[k][cc] = inb ? x[(((size_t)bb * 16 + cq * 4 + cc) * 192 + hh) * 192 + ww] : 0.f;
    }
}

__device__ __forceinline__ void halo_store(_Float16* __restrict__ dst, int tid,
                                           const float pfv[4][4])
{
#pragma unroll
    for (int k = 0; k < 4; ++k) {
        int u = tid + k * 512;
        if (u < HALO_UNITS) {
            int row = u / 264, rem = u % 264;
            int col = rem >> 2, cq = rem & 3;
            half4 hv;
#pragma unroll
            for (int cc = 0; cc < 4; ++cc) hv[cc] = (_Float16)pfv[k][cc];
            *(half4*)&dst[(row * 66 + col) * 16 + cq * 4] = hv;
        }
    }
}

__global__ __launch_bounds__(512, 2) void ca_main(
    const float* __restrict__ x,
    const float* __restrict__ b1g, const float* __restrict__ b2g,
    const float* __restrict__ b3g,
    const float* __restrict__ fire,
    const _Float16* __restrict__ wh,
    float* __restrict__ out,
    float* __restrict__ alpha_out)
{
    __shared__ __align__(16) struct {
        _Float16 w[WH_HALVES];          // 53248 B fragment-ordered weights
        _Float16 halo[2][6][66][16];    // 2 x 12672 B, channel-interleaved f16
        _Float16 h[16][2048];           // 16 frag-buffers (8 waves x 2) x 4KB
        float    b1[128], b2[128], b3[16];
    } s;

    const int tid  = threadIdx.x;
    const int lane = tid & 63;
    const int wave = tid >> 6;
    const int lr = lane & 15, hi = lane >> 4;

    // ---- prologue: stage weights (53248 B = 3328 uint4) ----
    {
        const uint4* src = (const uint4*)wh;
        uint4* dst = (uint4*)&s.w[0];
        for (int i = tid; i < 3328; i += 512) dst[i] = src[i];
    }
    if (tid < 128) { s.b1[tid] = b1g[tid]; s.b2[tid] = b2g[tid]; }
    if (tid < 16)  { s.b3[tid] = b3g[tid]; }

    // ---- prologue: halo for tile 0 into buf 0 ----
    {
        int t = blockIdx.x;
        int bb = t / 144, rem = t % 144;
        int h0 = (rem / 3) * 4, w0 = (rem % 3) * 64;
        float pfv[4][4];
        halo_loads(x, bb, h0, w0, tid, pfv);
        halo_store(&s.halo[0][0][0][0], tid, pfv);
    }
    __syncthreads();

    const half8* wf = (const half8*)s.w;
    const int swzh = ((lr >> 1) & 7) << 4;    // XOR bits 4-6 of in-row byte offset
    char* hb0 = (char*)&s.h[wave * 2][0];
    char* hb1 = (char*)&s.h[wave * 2 + 1][0];
    const int rowb = lr * 256;

    for (int it = 0; it < ITERS; ++it) {
        int t = blockIdx.x + it * NBLOCKS;
        int bb = t / 144, rem = t % 144;
        int h0 = (rem / 3) * 4, w0 = (rem % 3) * 64;
        const _Float16* hal = &s.halo[it & 1][0][0][0];

        // ---- T14: issue next tile's halo loads early ----
        float pfv[4][4];
        const bool have_next = (it + 1 < ITERS);
        if (have_next) {
            int tn = blockIdx.x + (it + 1) * NBLOCKS;
            int bbn = tn / 144, remn = tn % 144;
            halo_loads(x, bbn, (remn / 3) * 4, (remn % 3) * 64, tid, pfv);
        }

        // ---- fire for both frags ----
        int prowA[2], pcolA[2];
        float fn[2];
#pragma unroll
        for (int f = 0; f < 2; ++f) {
            int px = (wave * 2 + f) * 16 + lr;
            prowA[f] = px >> 6; pcolA[f] = px & 63;
            fn[f] = fire[(((size_t)bb) * 192 + h0 + prowA[f]) * 192 + w0 + pcolA[f]];
        }

        // ---- Sobel: 9 b128 taps per frag, packed-f16 math ----
        // a1[f][0]: hi0/1 = ctr c0-7/c8-15, hi2/3 = sx c0-7/c8-15
        // a1[f][1]: hi0/1 = sy  c0-7/c8-15, hi2/3 = zero (K pad)
        half8 a1[2][2];
        const half8 vz = { (_Float16)0.f, (_Float16)0.f, (_Float16)0.f, (_Float16)0.f,
                           (_Float16)0.f, (_Float16)0.f, (_Float16)0.f, (_Float16)0.f };
#pragma unroll
        for (int f = 0; f < 2; ++f) {
            half8 tp[3][3];
#pragma unroll
            for (int dr = 0; dr < 3; ++dr)
#pragma unroll
                for (int dc = 0; dc < 3; ++dc)
                    tp[dr][dc] = *(const half8*)&hal[((prowA[f] + dr) * 66 + pcolA[f] + dc) * 16 + (hi & 1) * 8];
            half8 gxa = (tp[0][2] - tp[0][0]) + (tp[2][2] - tp[2][0]);
            half8 gxb = (tp[1][2] - tp[1][0]);
            half8 gx  = gxa + gxb + gxb;
            half8 gya = (tp[2][0] - tp[0][0]) + (tp[2][2] - tp[0][2]);
            half8 gyb = (tp[2][1] - tp[0][1]);
            half8 gy  = gya + gyb + gyb;
            const _Float16 e = (_Float16)0.125f;
            gx = gx * e;
            gy = gy * e;
            a1[f][0] = (hi < 2) ? tp[1][1] : gx;
            a1[f][1] = (hi < 2) ? gy : vz;
        }

        // ========== Layer 1 (swapped): D[o][px], bias in C-init ==========
#pragma unroll
        for (int nb = 0; nb < 8; ++nb) {
            half8 bf0 = wf[(nb * 2    ) * 64 + lane];
            half8 bf1 = wf[(nb * 2 + 1) * 64 + lane];
            f32x4 bias = *(const f32x4*)&s.b1[nb * 16 + hi * 4];
            f32x4 acc0 = bias, acc1 = bias;
            acc0 = __builtin_amdgcn_mfma_f32_16x16x32_f16(bf0, a1[0][0], acc0, 0, 0, 0);
            acc0 = __builtin_amdgcn_mfma_f32_16x16x32_f16(bf1, a1[0][1], acc0, 0, 0, 0);
            acc1 = __builtin_amdgcn_mfma_f32_16x16x32_f16(bf0, a1[1][0], acc1, 0, 0, 0);
            acc1 = __builtin_amdgcn_mfma_f32_16x16x32_f16(bf1, a1[1][1], acc1, 0, 0, 0);
            half4 h0v, h1v;
#pragma unroll
            for (int rr = 0; rr < 4; ++rr) {
                h0v[rr] = (_Float16)fminf(fmaxf(acc0[rr], 0.f), 6.f);
                h1v[rr] = (_Float16)fminf(fmaxf(acc1[rr], 0.f), 6.f);
            }
            int off = (nb * 32 + hi * 8) ^ swzh;
            *(half4*)(hb0 + rowb + off) = h0v;
            *(half4*)(hb1 + rowb + off) = h1v;
        }

        // ========== Layer 2 (swapped, in-place h) ==========
        half8 a2[2][4];
#pragma unroll
        for (int kb = 0; kb < 4; ++kb) {
            int roff = (kb * 64 + hi * 16) ^ swzh;
            a2[0][kb] = *(const half8*)(hb0 + rowb + roff);
            a2[1][kb] = *(const half8*)(hb1 + rowb + roff);
        }
#pragma unroll
        for (int nb = 0; nb < 8; ++nb) {
            f32x4 bias = *(const f32x4*)&s.b2[nb * 16 + hi * 4];
            f32x4 acc0 = bias, acc1 = bias;
#pragma unroll
            for (int kb = 0; kb < 4; ++kb) {
                half8 bf = wf[1024 + (nb * 4 + kb) * 64 + lane];
                acc0 = __builtin_amdgcn_mfma_f32_16x16x32_f16(bf, a2[0][kb], acc0, 0, 0, 0);
                acc1 = __builtin_amdgcn_mfma_f32_16x16x32_f16(bf, a2[1][kb], acc1, 0, 0, 0);
            }
            half4 h0v, h1v;
#pragma unroll
            for (int rr = 0; rr < 4; ++rr) {
                h0v[rr] = (_Float16)fminf(fmaxf(acc0[rr], 0.f), 6.f);
                h1v[rr] = (_Float16)fminf(fmaxf(acc1[rr], 0.f), 6.f);
            }
            int off = (nb * 32 + hi * 8) ^ swzh;
            *(half4*)(hb0 + rowb + off) = h0v;
            *(half4*)(hb1 + rowb + off) = h1v;
        }

        // ========== Layer 3 (swapped): dx[c][px], c = hi*4+rr ==========
        half8 a3[2][4];
#pragma unroll
        for (int kb = 0; kb < 4; ++kb) {
            int roff = (kb * 64 + hi * 16) ^ swzh;
            a3[0][kb] = *(const half8*)(hb0 + rowb + roff);
            a3[1][kb] = *(const half8*)(hb1 + rowb + roff);
        }
        f32x4 acc3[2];
        acc3[0] = acc3[1] = *(const f32x4*)&s.b3[hi * 4];
#pragma unroll
        for (int kb = 0; kb < 4; ++kb) {
            half8 bf = wf[3072 + kb * 64 + lane];
            acc3[0] = __builtin_amdgcn_mfma_f32_16x16x32_f16(bf, a3[0][kb], acc3[0], 0, 0, 0);
            acc3[1] = __builtin_amdgcn_mfma_f32_16x16x32_f16(bf, a3[1][kb], acc3[1], 0, 0, 0);
        }

        // ---- epilogue: xc via one b64 (c-quad = hi), direct global store ----
#pragma unroll
        for (int f = 0; f < 2; ++f) {
            half4 xq = *(const half4*)&hal[((1 + prowA[f]) * 66 + 1 + pcolA[f]) * 16 + hi * 4];
            const bool upd = (fn[f] <= 0.5f);
            size_t obase = (((size_t)bb * 16) * 192 + h0 + prowA[f]) * 192 + w0 + pcolA[f];
#pragma unroll
            for (int rr = 0; rr < 4; ++rr) {
                int c = hi * 4 + rr;
                float xn = (float)xq[rr] + (upd ? acc3[f][rr] : 0.f);
                out[obase + (size_t)c * 36864] = xn;
                if (hi == 0 && rr == 3)
                    alpha_out[(((size_t)bb) * 192 + h0 + prowA[f]) * 192 + w0 + pcolA[f]] = xn;
            }
        }

        // ---- write prefetched next halo into the other buffer ----
        if (have_next)
            halo_store(&s.halo[(it + 1) & 1][0][0][0], tid, pfv);
        __syncthreads();
    }
}

__global__ __launch_bounds__(256) void ca_mask(
    const float* __restrict__ x,
    const float* __restrict__ alpha_new,
    float* __restrict__ out)
{
    int pix = blockIdx.x * 256 + threadIdx.x;   // exactly 16*192*192 threads
    int ww = pix % 192; int t = pix / 192;
    int hh = t % 192;   int bb = t / 192;
    float pre = -1e30f, post = -1e30f;
#pragma unroll
    for (int di = -1; di <= 1; ++di) {
        int nh = hh + di;
        if (nh < 0 || nh >= 192) continue;
#pragma unroll
        for (int dj = -1; dj <= 1; ++dj) {
            int nw = ww + dj;
            if (nw < 0 || nw >= 192) continue;
            pre  = fmaxf(pre,  x[(((size_t)bb * 16 + 3) * 192 + nh) * 192 + nw]);
            post = fmaxf(post, alpha_new[(((size_t)bb) * 192 + nh) * 192 + nw]);
        }
    }
    bool alive = (pre > 0.1f) && (post > 0.1f);
    if (alive) return;                 // life==1 -> out already holds x_new
#pragma unroll
    for (int c = 0; c < 16; ++c) {
        out[(((size_t)bb * 16 + c) * 192 + hh) * 192 + ww] = 0.f;
    }
}

extern "C" void kernel_launch(void* const* d_in, const int* in_sizes, int n_in,
                              void* d_out, int out_size, void* d_ws, size_t ws_size,
                              hipStream_t stream) {
    const float* x    = (const float*)d_in[0];
    const float* w1   = (const float*)d_in[1];
    const float* b1   = (const float*)d_in[2];
    const float* w2   = (const float*)d_in[3];
    const float* b2   = (const float*)d_in[4];
    const float* w3   = (const float*)d_in[5];
    const float* b3   = (const float*)d_in[6];
    const float* fire = (const float*)d_in[7];
    float* out = (float*)d_out;

    _Float16* wh     = (_Float16*)d_ws;
    float* alpha_new = (float*)((char*)d_ws + ALPHA_BYTE_OFF);

    prep_weights<<<104, 256, 0, stream>>>(w1, w2, w3, wh);
    ca_main<<<NBLOCKS, 512, 0, stream>>>(x, b1, b2, b3, fire, wh, out, alpha_new);
    ca_mask<<<2304, 256, 0, stream>>>(x, alpha_new, out);
}

// Round 7
// 73.471 us; speedup vs baseline: 1.2024x; 1.2024x over previous
//
#include <hip/hip_runtime.h>

typedef _Float16 half8 __attribute__((ext_vector_type(8)));
typedef _Float16 half4 __attribute__((ext_vector_type(4)));
typedef float    f32x4 __attribute__((ext_vector_type(4)));

// ws layout (halves), FRAGMENT-ORDERED for conflict-free ds_read_b128:
//   L1: frag f = nb*2 + vkb   (nb 0..7)          halves [0, 8192)
//   L2: frag f = nb*4 + kb    (nb 0..7, kb 0..3)  halves [8192, 24576)
//   L3: frag f = kb           (kb 0..3)           halves [24576, 26624)
//   wh[base + (f*64 + lane)*8 + j] = W[n = f_n*16 + (lane&15)][k = f_k*32 + (lane>>4)*8 + j]
#define WH_HALVES      26624
#define ALPHA_BYTE_OFF 53248

#define NBLOCKS  256
#define ITERS    9           // 2304 tiles of 4x64 px

__global__ __launch_bounds__(256) void prep_weights(
    const float* __restrict__ w1, const float* __restrict__ w2,
    const float* __restrict__ w3, _Float16* __restrict__ wh)
{
    int i = blockIdx.x * 256 + threadIdx.x;
    if (i >= WH_HALVES) return;
    int rem = i & 511;
    int l = rem >> 3, j = rem & 7;
    int lr = l & 15, lg = l >> 4;
    _Float16 v;
    if (i < 8192) {                       // L1: K padded 48->64
        int f = i >> 9;
        int nb = f >> 1, hh = f & 1;
        int o = nb * 16 + lr, k = hh * 32 + lg * 8 + j;
        v = (k < 48) ? (_Float16)w1[o * 48 + k] : (_Float16)0.f;
    } else if (i < 24576) {               // L2
        int f = (i - 8192) >> 9;
        int nb = f >> 2, kb = f & 3;
        v = (_Float16)w2[(nb * 16 + lr) * 128 + kb * 32 + lg * 8 + j];
    } else {                              // L3
        int kb = (i - 24576) >> 9;
        v = (_Float16)w3[lr * 128 + kb * 32 + lg * 8 + j];
    }
    wh[i] = v;
}

// halo staging units: (row 0..5, col 0..65, cq 0..3) -> 1584 b64 writes
#define HALO_UNITS 1584

__device__ __forceinline__ void halo_loads(const float* __restrict__ x,
                                           int bb, int h0, int w0, int tid,
                                           float pfv[2][4])
{
#pragma unroll
    for (int k = 0; k < 2; ++k) {
        int u = tid + k * 1024;
        bool valid = (u < HALO_UNITS);
        int uu = valid ? u : 0;
        int row = uu / 264, rem = uu % 264;
        int col = rem >> 2, cq = rem & 3;
        int hh = h0 - 1 + row, ww = w0 - 1 + col;
        bool inb = valid && hh >= 0 && hh < 192 && ww >= 0 && ww < 192;
#pragma unroll
        for (int cc = 0; cc < 4; ++cc)
            pfv[k][cc] = inb ? x[(((size_t)bb * 16 + cq * 4 + cc) * 192 + hh) * 192 + ww] : 0.f;
    }
}

__device__ __forceinline__ void halo_store(_Float16* __restrict__ dst, int tid,
                                           const float pfv[2][4])
{
#pragma unroll
    for (int k = 0; k < 2; ++k) {
        int u = tid + k * 1024;
        if (u < HALO_UNITS) {
            int row = u / 264, rem = u % 264;
            int col = rem >> 2, cq = rem & 3;
            half4 hv;
#pragma unroll
            for (int cc = 0; cc < 4; ++cc) hv[cc] = (_Float16)pfv[k][cc];
            *(half4*)&dst[(row * 66 + col) * 16 + cq * 4] = hv;
        }
    }
}

__global__ __launch_bounds__(1024, 4) void ca_main(
    const float* __restrict__ x,
    const float* __restrict__ b1g, const float* __restrict__ b2g,
    const float* __restrict__ b3g,
    const float* __restrict__ fire,
    const _Float16* __restrict__ wh,
    float* __restrict__ out,
    float* __restrict__ alpha_out)
{
    __shared__ __align__(16) struct {
        _Float16 w[WH_HALVES];          // 53248 B fragment-ordered weights
        _Float16 halo[2][6][66][16];    // 2 x 12672 B, channel-interleaved f16
        _Float16 h[16][2048];           // per-wave 4KB frag buffer (16 rows x 256B)
        float    b1[128], b2[128], b3[16];
    } s;

    const int tid  = threadIdx.x;
    const int lane = tid & 63;
    const int wave = tid >> 6;
    const int lr = lane & 15, hi = lane >> 4;

    // ---- prologue: stage weights (53248 B = 3328 uint4) ----
    {
        const uint4* src = (const uint4*)wh;
        uint4* dst = (uint4*)&s.w[0];
        for (int i = tid; i < 3328; i += 1024) dst[i] = src[i];
    }
    if (tid < 128) { s.b1[tid] = b1g[tid]; s.b2[tid] = b2g[tid]; }
    if (tid < 16)  { s.b3[tid] = b3g[tid]; }

    // ---- prologue: halo for tile 0 into buf 0 ----
    {
        int t = blockIdx.x;
        int bb = t / 144, rem = t % 144;
        int h0 = (rem / 3) * 4, w0 = (rem % 3) * 64;
        float pfv[2][4];
        halo_loads(x, bb, h0, w0, tid, pfv);
        halo_store(&s.halo[0][0][0][0], tid, pfv);
    }
    __syncthreads();

    const half8* wf = (const half8*)s.w;
    const int swzh = ((lr >> 1) & 7) << 4;    // XOR bits 4-6 of in-row byte offset
    char* hb = (char*)&s.h[wave][0];
    const int rowb = lr * 256;

    // this lane's pixel (B-operand column): px = wave*16 + lr
    const int px = wave * 16 + lr;
    const int prow = px >> 6, pcol = px & 63;

    for (int it = 0; it < ITERS; ++it) {
        int t = blockIdx.x + it * NBLOCKS;
        int bb = t / 144, rem = t % 144;
        int h0 = (rem / 3) * 4, w0 = (rem % 3) * 64;
        const _Float16* hal = &s.halo[it & 1][0][0][0];

        // ---- T14: issue next tile's halo loads early ----
        float pfv[2][4];
        const bool have_next = (it + 1 < ITERS);
        if (have_next) {
            int tn = blockIdx.x + (it + 1) * NBLOCKS;
            int bbn = tn / 144, remn = tn % 144;
            halo_loads(x, bbn, (remn / 3) * 4, (remn % 3) * 64, tid, pfv);
        }
        const float fn = fire[(((size_t)bb) * 192 + h0 + prow) * 192 + w0 + pcol];

        // ---- Sobel: 9 b128 taps, packed-f16 math ----
        // a1[0]: hi0/1 = ctr c0-7/c8-15, hi2/3 = sx c0-7/c8-15
        // a1[1]: hi0/1 = sy  c0-7/c8-15, hi2/3 = zero (K pad)
        half8 a1[2];
        {
            const half8 vz = { (_Float16)0.f, (_Float16)0.f, (_Float16)0.f, (_Float16)0.f,
                               (_Float16)0.f, (_Float16)0.f, (_Float16)0.f, (_Float16)0.f };
            half8 tp[3][3];
#pragma unroll
            for (int dr = 0; dr < 3; ++dr)
#pragma unroll
                for (int dc = 0; dc < 3; ++dc)
                    tp[dr][dc] = *(const half8*)&hal[((prow + dr) * 66 + pcol + dc) * 16 + (hi & 1) * 8];
            half8 gxa = (tp[0][2] - tp[0][0]) + (tp[2][2] - tp[2][0]);
            half8 gxb = (tp[1][2] - tp[1][0]);
            half8 gx  = gxa + gxb + gxb;
            half8 gya = (tp[2][0] - tp[0][0]) + (tp[2][2] - tp[0][2]);
            half8 gyb = (tp[2][1] - tp[0][1]);
            half8 gy  = gya + gyb + gyb;
            const _Float16 e = (_Float16)0.125f;
            gx = gx * e;
            gy = gy * e;
            a1[0] = (hi < 2) ? tp[1][1] : gx;
            a1[1] = (hi < 2) ? gy : vz;
        }

        // ========== Layer 1 (swapped): D[o][px], bias in C-init ==========
#pragma unroll
        for (int nb = 0; nb < 8; ++nb) {
            half8 bf0 = wf[(nb * 2    ) * 64 + lane];
            half8 bf1 = wf[(nb * 2 + 1) * 64 + lane];
            f32x4 acc = *(const f32x4*)&s.b1[nb * 16 + hi * 4];
            acc = __builtin_amdgcn_mfma_f32_16x16x32_f16(bf0, a1[0], acc, 0, 0, 0);
            acc = __builtin_amdgcn_mfma_f32_16x16x32_f16(bf1, a1[1], acc, 0, 0, 0);
            half4 hv;
#pragma unroll
            for (int rr = 0; rr < 4; ++rr)
                hv[rr] = (_Float16)fminf(fmaxf(acc[rr], 0.f), 6.f);
            *(half4*)(hb + rowb + ((nb * 32 + hi * 8) ^ swzh)) = hv;   // o=nb*16+hi*4+rr
        }

        // ========== Layer 2 (swapped, in-place h) ==========
        half8 a2[4];
#pragma unroll
        for (int kb = 0; kb < 4; ++kb)
            a2[kb] = *(const half8*)(hb + rowb + ((kb * 64 + hi * 16) ^ swzh));
#pragma unroll
        for (int nb = 0; nb < 8; ++nb) {
            f32x4 acc = *(const f32x4*)&s.b2[nb * 16 + hi * 4];
#pragma unroll
            for (int kb = 0; kb < 4; ++kb) {
                half8 bf = wf[1024 + (nb * 4 + kb) * 64 + lane];
                acc = __builtin_amdgcn_mfma_f32_16x16x32_f16(bf, a2[kb], acc, 0, 0, 0);
            }
            half4 hv;
#pragma unroll
            for (int rr = 0; rr < 4; ++rr)
                hv[rr] = (_Float16)fminf(fmaxf(acc[rr], 0.f), 6.f);
            *(half4*)(hb + rowb + ((nb * 32 + hi * 8) ^ swzh)) = hv;
        }

        // ========== Layer 3 (swapped): dx[c][px], c = hi*4+rr ==========
        half8 a3[4];
#pragma unroll
        for (int kb = 0; kb < 4; ++kb)
            a3[kb] = *(const half8*)(hb + rowb + ((kb * 64 + hi * 16) ^ swzh));
        f32x4 acc3 = *(const f32x4*)&s.b3[hi * 4];
#pragma unroll
        for (int kb = 0; kb < 4; ++kb) {
            half8 bf = wf[3072 + kb * 64 + lane];
            acc3 = __builtin_amdgcn_mfma_f32_16x16x32_f16(bf, a3[kb], acc3, 0, 0, 0);
        }

        // ---- epilogue: xc via one b64 (c-quad = hi), direct global store ----
        {
            half4 xq = *(const half4*)&hal[((1 + prow) * 66 + 1 + pcol) * 16 + hi * 4];
            const bool upd = (fn <= 0.5f);
            size_t obase = (((size_t)bb * 16) * 192 + h0 + prow) * 192 + w0 + pcol;
#pragma unroll
            for (int rr = 0; rr < 4; ++rr) {
                int c = hi * 4 + rr;
                float xn = (float)xq[rr] + (upd ? acc3[rr] : 0.f);
                out[obase + (size_t)c * 36864] = xn;
                if (hi == 0 && rr == 3)
                    alpha_out[(((size_t)bb) * 192 + h0 + prow) * 192 + w0 + pcol] = xn;
            }
        }

        // ---- write prefetched next halo into the other buffer ----
        if (have_next)
            halo_store(&s.halo[(it + 1) & 1][0][0][0], tid, pfv);
        __syncthreads();
    }
}

__global__ __launch_bounds__(256) void ca_mask(
    const float* __restrict__ x,
    const float* __restrict__ alpha_new,
    float* __restrict__ out)
{
    int pix = blockIdx.x * 256 + threadIdx.x;   // exactly 16*192*192 threads
    int ww = pix % 192; int t = pix / 192;
    int hh = t % 192;   int bb = t / 192;
    float pre = -1e30f, post = -1e30f;
#pragma unroll
    for (int di = -1; di <= 1; ++di) {
        int nh = hh + di;
        if (nh < 0 || nh >= 192) continue;
#pragma unroll
        for (int dj = -1; dj <= 1; ++dj) {
            int nw = ww + dj;
            if (nw < 0 || nw >= 192) continue;
            pre  = fmaxf(pre,  x[(((size_t)bb * 16 + 3) * 192 + nh) * 192 + nw]);
            post = fmaxf(post, alpha_new[(((size_t)bb) * 192 + nh) * 192 + nw]);
        }
    }
    bool alive = (pre > 0.1f) && (post > 0.1f);
    if (alive) return;                 // life==1 -> out already holds x_new
#pragma unroll
    for (int c = 0; c < 16; ++c) {
        out[(((size_t)bb * 16 + c) * 192 + hh) * 192 + ww] = 0.f;
    }
}

extern "C" void kernel_launch(void* const* d_in, const int* in_sizes, int n_in,
                              void* d_out, int out_size, void* d_ws, size_t ws_size,
                              hipStream_t stream) {
    const float* x    = (const float*)d_in[0];
    const float* w1   = (const float*)d_in[1];
    const float* b1   = (const float*)d_in[2];
    const float* w2   = (const float*)d_in[3];
    const float* b2   = (const float*)d_in[4];
    const float* w3   = (const float*)d_in[5];
    const float* b3   = (const float*)d_in[6];
    const float* fire = (const float*)d_in[7];
    float* out = (float*)d_out;

    _Float16* wh     = (_Float16*)d_ws;
    float* alpha_new = (float*)((char*)d_ws + ALPHA_BYTE_OFF);

    prep_weights<<<104, 256, 0, stream>>>(w1, w2, w3, wh);
    ca_main<<<NBLOCKS, 1024, 0, stream>>>(x, b1, b2, b3, fire, wh, out, alpha_new);
    ca_mask<<<2304, 256, 0, stream>>>(x, alpha_new, out);
}

// Round 9
// 69.527 us; speedup vs baseline: 1.2706x; 1.0567x over previous
//
#include <hip/hip_runtime.h>

typedef _Float16 half8  __attribute__((ext_vector_type(8)));
typedef _Float16 half4  __attribute__((ext_vector_type(4)));
typedef _Float16 half2v __attribute__((ext_vector_type(2)));
typedef float    f32x4  __attribute__((ext_vector_type(4)));
typedef float    f32x16 __attribute__((ext_vector_type(16)));

// ws layout (halves), 32x32x16 FRAGMENT-ORDERED:
//   L1: f = nb*3 + kb   (nb 0..3, kb 0..2)   K=48 exact
//   L2: f = 12 + nb*8 + kb (nb 0..3, kb 0..7)
//   L3: f = 44 + kb     (kb 0..7; o 16..31 zero-padded)
//   wh[f*512 + l*8 + j] = W[o = f_n*32 + (l&31)][k = f_k*16 + (l>>5)*8 + j]
#define WH_HALVES      26624
#define ALPHA_BYTE_OFF 53248

#define NBLOCKS  256
#define NTILES   1152      // 16 bb * 24 vtiles * 3 seg, tile = 8 rows x 64 cols

__global__ __launch_bounds__(256) void prep_weights(
    const float* __restrict__ w1, const float* __restrict__ w2,
    const float* __restrict__ w3, _Float16* __restrict__ wh)
{
    int i = blockIdx.x * 256 + threadIdx.x;
    if (i >= WH_HALVES) return;
    int f = i >> 9, rem = i & 511;
    int l = rem >> 3, j = rem & 7;
    int l31 = l & 31, hi = l >> 5;
    _Float16 v;
    if (f < 12) {
        int nb = f / 3, kb = f % 3;
        v = (_Float16)w1[(nb * 32 + l31) * 48 + kb * 16 + hi * 8 + j];
    } else if (f < 44) {
        int ff = f - 12, nb = ff >> 3, kb = ff & 7;
        v = (_Float16)w2[(nb * 32 + l31) * 128 + kb * 16 + hi * 8 + j];
    } else {
        int kb = f - 44;
        v = (l31 < 16) ? (_Float16)w3[l31 * 128 + kb * 16 + hi * 8 + j] : (_Float16)0.f;
    }
    wh[i] = v;
}

#define HALO_UNITS 2640    // 10 rows * 66 cols * 4 cq

__device__ __forceinline__ void halo_loads(const float* __restrict__ x,
                                           int bb, int h0, int w0, int tid,
                                           float pfv[3][4])
{
#pragma unroll
    for (int k = 0; k < 3; ++k) {
        int u = tid + k * 1024;
        bool valid = (u < HALO_UNITS);
        int uu = valid ? u : 0;
        int row = uu / 264, rem = uu % 264;
        int col = rem >> 2, cq = rem & 3;
        int hh = h0 - 1 + row, ww = w0 - 1 + col;
        bool inb = valid && hh >= 0 && hh < 192 && ww >= 0 && ww < 192;
#pragma unroll
        for (int cc = 0; cc < 4; ++cc)
            pfv[k][cc] = inb ? x[(((size_t)bb * 16 + cq * 4 + cc) * 192 + hh) * 192 + ww] : 0.f;
    }
}

__device__ __forceinline__ void halo_store(_Float16* __restrict__ dst, int tid,
                                           const float pfv[3][4])
{
#pragma unroll
    for (int k = 0; k < 3; ++k) {
        int u = tid + k * 1024;
        if (u < HALO_UNITS) {
            int row = u / 264, rem = u % 264;
            int col = rem >> 2, cq = rem & 3;
            half4 hv;
#pragma unroll
            for (int cc = 0; cc < 4; ++cc) hv[cc] = (_Float16)pfv[k][cc];
            *(half4*)&dst[(row * 66 + col) * 16 + cq * 4] = hv;
        }
    }
}

// relu6 -> f16 pack -> permlane32_swap: D regs (o-major) -> next-layer B-frags.
// D: lane(px=l&31, hiD=l>>5) reg r holds o = base + (r&3)+8*(r>>2)+4*hiD.
// B: lane(px, hi32) word j' holds k = base' + hi32*8 + {2j',2j'+1}.
// ISA: v_permlane32_swap_b32 vdst,vsrc swaps vdst rows 32-63 with vsrc rows
// 0-31  =>  swap(X,Y): X' = [X.low|Y.low], Y' = [X.high|Y.high].
// word0 = [P0.low|P2.low] -> swap(P0,P2); word2 = [P0.high|P2.high] = P2'.
__device__ __forceinline__ void make_frags(const f32x16 acc, half8* fa, half8* fb)
{
    unsigned P[8];
#pragma unroll
    for (int w = 0; w < 8; ++w) {
        half2v pk;
        pk[0] = (_Float16)fminf(fmaxf(acc[2 * w    ], 0.f), 6.f);
        pk[1] = (_Float16)fminf(fmaxf(acc[2 * w + 1], 0.f), 6.f);
        P[w] = __builtin_bit_cast(unsigned, pk);
    }
    asm volatile("v_permlane32_swap_b32 %0, %1" : "+v"(P[0]), "+v"(P[2]));
    asm volatile("v_permlane32_swap_b32 %0, %1" : "+v"(P[1]), "+v"(P[3]));
    asm volatile("v_permlane32_swap_b32 %0, %1" : "+v"(P[4]), "+v"(P[6]));
    asm volatile("v_permlane32_swap_b32 %0, %1" : "+v"(P[5]), "+v"(P[7]));
    union { unsigned u[4]; half8 h; } A, B;
    A.u[0] = P[0]; A.u[1] = P[1]; A.u[2] = P[2]; A.u[3] = P[3];
    B.u[0] = P[4]; B.u[1] = P[5]; B.u[2] = P[6]; B.u[3] = P[7];
    *fa = A.h; *fb = B.h;
}

__global__ __launch_bounds__(1024, 4) void ca_main(
    const float* __restrict__ x,
    const float* __restrict__ b1g, const float* __restrict__ b2g,
    const float* __restrict__ b3g,
    const float* __restrict__ fire,
    const _Float16* __restrict__ wh,
    float* __restrict__ out,
    float* __restrict__ alpha_out)
{
    __shared__ __align__(16) struct {
        _Float16 w[WH_HALVES];          // 53248 B fragment-ordered weights
        _Float16 halo[2][10][66][16];   // 2 x 21120 B, channel-interleaved f16
        __align__(64) float b1d[4][2][16];   // biases in D-row order
        __align__(64) float b2d[4][2][16];
        __align__(64) float b3d[2][16];
    } s;

    const int tid  = threadIdx.x;
    const int lane = tid & 63;
    const int wave = tid >> 6;
    const int l31 = lane & 31, hi = lane >> 5;

    // ---- prologue: weights (53248 B = 3328 uint4) ----
    {
        const uint4* src = (const uint4*)wh;
        uint4* dst = (uint4*)&s.w[0];
        for (int i = tid; i < 3328; i += 1024) dst[i] = src[i];
    }
    // ---- biases into D-row order: b[nb][hiD][r] = bias[nb*32+(r&3)+8*(r>>2)+4*hiD]
    if (tid < 128) {
        int o = tid, nb = o >> 5, ol = o & 31;
        int r = (ol & 3) + 4 * (ol >> 3), hd = (ol >> 2) & 1;
        s.b1d[nb][hd][r] = b1g[o];
        s.b2d[nb][hd][r] = b2g[o];
    }
    if (tid < 32) {
        int hd = tid >> 4, r = tid & 15;
        s.b3d[hd][r] = (r < 8) ? b3g[(r & 3) + 8 * (r >> 2) + 4 * hd] : 0.f;
    }
    // ---- halo for tile 0 ----
    {
        int t = blockIdx.x;
        int bb = t / 72, rem = t % 72;
        int h0 = (rem / 3) * 8, w0 = (rem % 3) * 64;
        float pfv[3][4];
        halo_loads(x, bb, h0, w0, tid, pfv);
        halo_store(&s.halo[0][0][0][0], tid, pfv);
    }
    __syncthreads();

    const half8* wf = (const half8*)s.w;
    const int px = wave * 32 + l31;         // this lane's pixel (B col = lane&31)
    const int prow = px >> 6, pcol = px & 63;

    for (int it = 0; ; ++it) {
        int t = blockIdx.x + it * NBLOCKS;
        if (t >= NTILES) break;
        int bb = t / 72, rem = t % 72;
        int h0 = (rem / 3) * 8, w0 = (rem % 3) * 64;
        const _Float16* hal = &s.halo[it & 1][0][0][0];

        // ---- T14: next tile's halo loads issued early ----
        float pfv[3][4];
        int tn = t + NBLOCKS;
        const bool have_next = (tn < NTILES);
        if (have_next) {
            int bbn = tn / 72, remn = tn % 72;
            halo_loads(x, bbn, (remn / 3) * 8, (remn % 3) * 64, tid, pfv);
        }
        const float fn = fire[(((size_t)bb) * 192 + h0 + prow) * 192 + w0 + pcol];

        // ---- Sobel: 9 b128 taps -> 3 B-frags (K=48 exact; k-split = hi*8+j = channel) ----
        half8 bs0, bs1, bs2;
        {
            half8 tp[3][3];
#pragma unroll
            for (int dr = 0; dr < 3; ++dr)
#pragma unroll
                for (int dc = 0; dc < 3; ++dc)
                    tp[dr][dc] = *(const half8*)&hal[((prow + dr) * 66 + pcol + dc) * 16 + hi * 8];
            half8 gxa = (tp[0][2] - tp[0][0]) + (tp[2][2] - tp[2][0]);
            half8 gxb = (tp[1][2] - tp[1][0]);
            half8 gx  = gxa + gxb + gxb;
            half8 gya = (tp[2][0] - tp[0][0]) + (tp[2][2] - tp[0][2]);
            half8 gyb = (tp[2][1] - tp[0][1]);
            half8 gy  = gya + gyb + gyb;
            const _Float16 e = (_Float16)0.125f;
            bs0 = tp[1][1];
            bs1 = gx * e;
            bs2 = gy * e;
        }

        // ========== Layer 1: 12 MFMAs -> in-register -> L2 B-frags ==========
        half8 l2b[8];
#pragma unroll
        for (int nb = 0; nb < 4; ++nb) {
            f32x16 acc = *(const f32x16*)&s.b1d[nb][hi][0];
            acc = __builtin_amdgcn_mfma_f32_32x32x16_f16(wf[(nb * 3 + 0) * 64 + lane], bs0, acc, 0, 0, 0);
            acc = __builtin_amdgcn_mfma_f32_32x32x16_f16(wf[(nb * 3 + 1) * 64 + lane], bs1, acc, 0, 0, 0);
            acc = __builtin_amdgcn_mfma_f32_32x32x16_f16(wf[(nb * 3 + 2) * 64 + lane], bs2, acc, 0, 0, 0);
            make_frags(acc, &l2b[2 * nb], &l2b[2 * nb + 1]);
        }

        // ========== Layer 2: 32 MFMAs -> L3 B-frags ==========
        half8 l3b[8];
#pragma unroll
        for (int nb = 0; nb < 4; ++nb) {
            f32x16 acc = *(const f32x16*)&s.b2d[nb][hi][0];
#pragma unroll
            for (int kb = 0; kb < 8; ++kb)
                acc = __builtin_amdgcn_mfma_f32_32x32x16_f16(wf[(12 + nb * 8 + kb) * 64 + lane], l2b[kb], acc, 0, 0, 0);
            make_frags(acc, &l3b[2 * nb], &l3b[2 * nb + 1]);
        }

        // ========== Layer 3: 8 MFMAs (N=32, o>=16 zero) ==========
        f32x16 acc3 = *(const f32x16*)&s.b3d[hi][0];
#pragma unroll
        for (int kb = 0; kb < 8; ++kb)
            acc3 = __builtin_amdgcn_mfma_f32_32x32x16_f16(wf[(44 + kb) * 64 + lane], l3b[kb], acc3, 0, 0, 0);

        // ---- epilogue: regs r0..7 hold c = (r&3)+8*(r>>2)+4*hi of this px ----
        {
            half4 xq0 = *(const half4*)&hal[((1 + prow) * 66 + 1 + pcol) * 16 + hi * 4];
            half4 xq1 = *(const half4*)&hal[((1 + prow) * 66 + 1 + pcol) * 16 + 8 + hi * 4];
            const bool upd = (fn <= 0.5f);
            size_t obase = (((size_t)bb * 16) * 192 + h0 + prow) * 192 + w0 + pcol;
#pragma unroll
            for (int r = 0; r < 8; ++r) {
                int c = (r & 3) + 8 * (r >> 2) + 4 * hi;
                float xc = (float)((r < 4) ? xq0[r & 3] : xq1[r & 3]);
                float xn = xc + (upd ? acc3[r] : 0.f);
                out[obase + (size_t)c * 36864] = xn;
                if (hi == 0 && r == 3)
                    alpha_out[(((size_t)bb) * 192 + h0 + prow) * 192 + w0 + pcol] = xn;
            }
        }

        // ---- write prefetched next halo into the other buffer ----
        if (have_next)
            halo_store(&s.halo[(it + 1) & 1][0][0][0], tid, pfv);
        __syncthreads();
    }
}

__global__ __launch_bounds__(256) void ca_mask(
    const float* __restrict__ x,
    const float* __restrict__ alpha_new,
    float* __restrict__ out)
{
    int pix = blockIdx.x * 256 + threadIdx.x;   // exactly 16*192*192 threads
    int ww = pix % 192; int t = pix / 192;
    int hh = t % 192;   int bb = t / 192;
    float pre = -1e30f, post = -1e30f;
#pragma unroll
    for (int di = -1; di <= 1; ++di) {
        int nh = hh + di;
        if (nh < 0 || nh >= 192) continue;
#pragma unroll
        for (int dj = -1; dj <= 1; ++dj) {
            int nw = ww + dj;
            if (nw < 0 || nw >= 192) continue;
            pre  = fmaxf(pre,  x[(((size_t)bb * 16 + 3) * 192 + nh) * 192 + nw]);
            post = fmaxf(post, alpha_new[(((size_t)bb) * 192 + nh) * 192 + nw]);
        }
    }
    bool alive = (pre > 0.1f) && (post > 0.1f);
    if (alive) return;                 // life==1 -> out already holds x_new
#pragma unroll
    for (int c = 0; c < 16; ++c) {
        out[(((size_t)bb * 16 + c) * 192 + hh) * 192 + ww] = 0.f;
    }
}

extern "C" void kernel_launch(void* const* d_in, const int* in_sizes, int n_in,
                              void* d_out, int out_size, void* d_ws, size_t ws_size,
                              hipStream_t stream) {
    const float* x    = (const float*)d_in[0];
    const float* w1   = (const float*)d_in[1];
    const float* b1   = (const float*)d_in[2];
    const float* w2   = (const float*)d_in[3];
    const float* b2   = (const float*)d_in[4];
    const float* w3   = (const float*)d_in[5];
    const float* b3   = (const float*)d_in[6];
    const float* fire = (const float*)d_in[7];
    float* out = (float*)d_out;

    _Float16* wh     = (_Float16*)d_ws;
    float* alpha_new = (float*)((char*)d_ws + ALPHA_BYTE_OFF);

    prep_weights<<<104, 256, 0, stream>>>(w1, w2, w3, wh);
    ca_main<<<NBLOCKS, 1024, 0, stream>>>(x, b1, b2, b3, fire, wh, out, alpha_new);
    ca_mask<<<2304, 256, 0, stream>>>(x, alpha_new, out);
}

// Round 11
// 65.656 us; speedup vs baseline: 1.3455x; 1.0590x over previous
//
#include <hip/hip_runtime.h>

typedef _Float16 half8  __attribute__((ext_vector_type(8)));
typedef _Float16 half4  __attribute__((ext_vector_type(4)));
typedef float    f32x4  __attribute__((ext_vector_type(4)));
typedef float    f32x16 __attribute__((ext_vector_type(16)));

// ws layout (halves), 32x32x16 FRAGMENT-ORDERED (verified R9):
//   L1: f = nb*3 + kb   (nb 0..3, kb 0..2)   K=48 exact
//   L2: f = 12 + nb*8 + kb (nb 0..3, kb 0..7)
//   L3: f = 44 + kb     (kb 0..7; o 16..31 zero-padded)
//   wh[f*512 + l*8 + j] = W[o = f_n*32 + (l&31)][k = f_k*16 + (l>>5)*8 + j]
#define WH_HALVES      26624
#define ALPHA_BYTE_OFF 53248

#define NBLOCKS  512
#define NTILES   2304      // 16 bb * 24 vtiles * 6 wseg, tile = 8 rows x 32 cols

__global__ __launch_bounds__(256) void prep_weights(
    const float* __restrict__ w1, const float* __restrict__ w2,
    const float* __restrict__ w3, _Float16* __restrict__ wh)
{
    int i = blockIdx.x * 256 + threadIdx.x;
    if (i >= WH_HALVES) return;
    int f = i >> 9, rem = i & 511;
    int l = rem >> 3, j = rem & 7;
    int l31 = l & 31, hi = l >> 5;
    _Float16 v;
    if (f < 12) {
        int nb = f / 3, kb = f % 3;
        v = (_Float16)w1[(nb * 32 + l31) * 48 + kb * 16 + hi * 8 + j];
    } else if (f < 44) {
        int ff = f - 12, nb = ff >> 3, kb = ff & 7;
        v = (_Float16)w2[(nb * 32 + l31) * 128 + kb * 16 + hi * 8 + j];
    } else {
        int kb = f - 44;
        v = (l31 < 16) ? (_Float16)w3[l31 * 128 + kb * 16 + hi * 8 + j] : (_Float16)0.f;
    }
    wh[i] = v;
}

#define HALO_UNITS 1360    // 10 rows * 34 cols * 4 cq

__device__ __forceinline__ void halo_loads(const float* __restrict__ x,
                                           int bb, int h0, int w0, int tid,
                                           float pfv[3][4])
{
#pragma unroll
    for (int k = 0; k < 3; ++k) {
        int u = tid + k * 512;
        bool valid = (u < HALO_UNITS);
        int uu = valid ? u : 0;
        int row = uu / 136, rem = uu % 136;
        int col = rem >> 2, cq = rem & 3;
        int hh = h0 - 1 + row, ww = w0 - 1 + col;
        bool inb = valid && hh >= 0 && hh < 192 && ww >= 0 && ww < 192;
#pragma unroll
        for (int cc = 0; cc < 4; ++cc)
            pfv[k][cc] = inb ? x[(((size_t)bb * 16 + cq * 4 + cc) * 192 + hh) * 192 + ww] : 0.f;
    }
}

__device__ __forceinline__ void halo_store(_Float16* __restrict__ dst, int tid,
                                           const float pfv[3][4])
{
#pragma unroll
    for (int k = 0; k < 3; ++k) {
        int u = tid + k * 512;
        if (u < HALO_UNITS) {
            int row = u / 136, rem = u % 136;
            int col = rem >> 2, cq = rem & 3;
            half4 hv;
#pragma unroll
            for (int cc = 0; cc < 4; ++cc) hv[cc] = (_Float16)pfv[k][cc];
            *(half4*)&dst[(row * 34 + col) * 16 + cq * 4] = hv;
        }
    }
}

// relu6(fmed3) -> cvt_pkrtz pack -> permlane32_swap: D regs -> next-layer B-frags.
// D: lane(px=l&31, hiD=l>>5) reg r holds o = base + (r&3)+8*(r>>2)+4*hiD.
// B: lane(px, hi32) word j' holds k = base' + hi32*8 + {2j',2j'+1}.
// ISA: swap(X,Y): X' = [X.low|Y.low], Y' = [X.high|Y.high]  (verified R9).
__device__ __forceinline__ void make_frags(const f32x16 acc, half8* fa, half8* fb)
{
    unsigned P[8];
#pragma unroll
    for (int w = 0; w < 8; ++w) {
        float lo = __builtin_amdgcn_fmed3f(acc[2 * w    ], 0.f, 6.f);
        float hh = __builtin_amdgcn_fmed3f(acc[2 * w + 1], 0.f, 6.f);
        P[w] = __builtin_bit_cast(unsigned, __builtin_amdgcn_cvt_pkrtz(lo, hh));
    }
    asm volatile("v_permlane32_swap_b32 %0, %1" : "+v"(P[0]), "+v"(P[2]));
    asm volatile("v_permlane32_swap_b32 %0, %1" : "+v"(P[1]), "+v"(P[3]));
    asm volatile("v_permlane32_swap_b32 %0, %1" : "+v"(P[4]), "+v"(P[6]));
    asm volatile("v_permlane32_swap_b32 %0, %1" : "+v"(P[5]), "+v"(P[7]));
    union { unsigned u[4]; half8 h; } A, B;
    A.u[0] = P[0]; A.u[1] = P[1]; A.u[2] = P[2]; A.u[3] = P[3];
    B.u[0] = P[4]; B.u[1] = P[5]; B.u[2] = P[6]; B.u[3] = P[7];
    *fa = A.h; *fb = B.h;
}

__global__ __launch_bounds__(512, 4) void ca_main(
    const float* __restrict__ x,
    const float* __restrict__ b1g, const float* __restrict__ b2g,
    const float* __restrict__ b3g,
    const float* __restrict__ fire,
    const _Float16* __restrict__ wh,
    float* __restrict__ out,
    float* __restrict__ alpha_out)
{
    __shared__ __align__(16) struct {
        _Float16 w[WH_HALVES];          // 53248 B fragment-ordered weights
        _Float16 halo[2][10][34][16];   // 2 x 10880 B, channel-interleaved f16
        __align__(64) float b1d[4][2][16];   // biases in D-row order
        __align__(64) float b2d[4][2][16];
        __align__(64) float b3d[2][16];
    } s;    // total ~76.2 KB -> 2 blocks/CU

    const int tid  = threadIdx.x;
    const int lane = tid & 63;
    const int wave = tid >> 6;            // 0..7 = tile row
    const int l31 = lane & 31, hi = lane >> 5;

    // ---- prologue: weights (53248 B = 3328 uint4) ----
    {
        const uint4* src = (const uint4*)wh;
        uint4* dst = (uint4*)&s.w[0];
        for (int i = tid; i < 3328; i += 512) dst[i] = src[i];
    }
    // ---- biases into D-row order: b[nb][hiD][r] = bias[nb*32+(r&3)+8*(r>>2)+4*hiD]
    if (tid < 128) {
        int o = tid, nb = o >> 5, ol = o & 31;
        int r = (ol & 3) + 4 * (ol >> 3), hd = (ol >> 2) & 1;
        s.b1d[nb][hd][r] = b1g[o];
        s.b2d[nb][hd][r] = b2g[o];
    }
    if (tid < 32) {
        int hd = tid >> 4, r = tid & 15;
        s.b3d[hd][r] = (r < 8) ? b3g[(r & 3) + 8 * (r >> 2) + 4 * hd] : 0.f;
    }
    // ---- halo for tile 0 ----
    {
        int t = blockIdx.x;
        int bb = t / 144, rem = t % 144;
        int h0 = (rem / 6) * 8, w0 = (rem % 6) * 32;
        float pfv[3][4];
        halo_loads(x, bb, h0, w0, tid, pfv);
        halo_store(&s.halo[0][0][0][0], tid, pfv);
    }
    __syncthreads();

    const half8* wf = (const half8*)s.w;
    const int prow = wave, pcol = l31;       // tile 8x32: wave = row, l31 = col
    const f32x16 b3reg = *(const f32x16*)&s.b3d[hi][0];   // hoisted (16 VGPR)

    for (int it = 0; ; ++it) {
        int t = blockIdx.x + it * NBLOCKS;
        if (t >= NTILES) break;
        int bb = t / 144, rem = t % 144;
        int h0 = (rem / 6) * 8, w0 = (rem % 6) * 32;
        const _Float16* hal = &s.halo[it & 1][0][0][0];

        // ---- T14: next tile's halo loads issued early ----
        float pfv[3][4];
        int tn = t + NBLOCKS;
        const bool have_next = (tn < NTILES);
        if (have_next) {
            int bbn = tn / 144, remn = tn % 144;
            halo_loads(x, bbn, (remn / 6) * 8, (remn % 6) * 32, tid, pfv);
        }
        const float fn = fire[(((size_t)bb) * 192 + h0 + prow) * 192 + w0 + pcol];

        // ---- Sobel: 9 b128 taps -> 3 B-frags (K=48 exact; k = hi*8+j = channel) ----
        half8 bs0, bs1, bs2;
        {
            half8 tp[3][3];
#pragma unroll
            for (int dr = 0; dr < 3; ++dr)
#pragma unroll
                for (int dc = 0; dc < 3; ++dc)
                    tp[dr][dc] = *(const half8*)&hal[((prow + dr) * 34 + pcol + dc) * 16 + hi * 8];
            half8 gxa = (tp[0][2] - tp[0][0]) + (tp[2][2] - tp[2][0]);
            half8 gxb = (tp[1][2] - tp[1][0]);
            half8 gx  = gxa + gxb + gxb;
            half8 gya = (tp[2][0] - tp[0][0]) + (tp[2][2] - tp[0][2]);
            half8 gyb = (tp[2][1] - tp[0][1]);
            half8 gy  = gya + gyb + gyb;
            const _Float16 e = (_Float16)0.125f;
            bs0 = tp[1][1];
            bs1 = gx * e;
            bs2 = gy * e;
        }

        // ========== Layer 1: 12 MFMAs -> in-register -> L2 B-frags ==========
        half8 l2b[8];
#pragma unroll
        for (int nb = 0; nb < 4; ++nb) {
            f32x16 acc = *(const f32x16*)&s.b1d[nb][hi][0];
            acc = __builtin_amdgcn_mfma_f32_32x32x16_f16(wf[(nb * 3 + 0) * 64 + lane], bs0, acc, 0, 0, 0);
            acc = __builtin_amdgcn_mfma_f32_32x32x16_f16(wf[(nb * 3 + 1) * 64 + lane], bs1, acc, 0, 0, 0);
            acc = __builtin_amdgcn_mfma_f32_32x32x16_f16(wf[(nb * 3 + 2) * 64 + lane], bs2, acc, 0, 0, 0);
            make_frags(acc, &l2b[2 * nb], &l2b[2 * nb + 1]);
        }

        // ========== Layer 2: 32 MFMAs -> L3 B-frags ==========
        half8 l3b[8];
#pragma unroll
        for (int nb = 0; nb < 4; ++nb) {
            f32x16 acc = *(const f32x16*)&s.b2d[nb][hi][0];
#pragma unroll
            for (int kb = 0; kb < 8; ++kb)
                acc = __builtin_amdgcn_mfma_f32_32x32x16_f16(wf[(12 + nb * 8 + kb) * 64 + lane], l2b[kb], acc, 0, 0, 0);
            make_frags(acc, &l3b[2 * nb], &l3b[2 * nb + 1]);
        }

        // ========== Layer 3: 8 MFMAs (N=32, o>=16 zero) ==========
        f32x16 acc3 = b3reg;
#pragma unroll
        for (int kb = 0; kb < 8; ++kb)
            acc3 = __builtin_amdgcn_mfma_f32_32x32x16_f16(wf[(44 + kb) * 64 + lane], l3b[kb], acc3, 0, 0, 0);

        // ---- epilogue: regs r0..7 hold c = (r&3)+8*(r>>2)+4*hi of this px ----
        {
            half4 xq0 = *(const half4*)&hal[((1 + prow) * 34 + 1 + pcol) * 16 + hi * 4];
            half4 xq1 = *(const half4*)&hal[((1 + prow) * 34 + 1 + pcol) * 16 + 8 + hi * 4];
            const bool upd = (fn <= 0.5f);
            size_t obase = (((size_t)bb * 16) * 192 + h0 + prow) * 192 + w0 + pcol;
#pragma unroll
            for (int r = 0; r < 8; ++r) {
                int c = (r & 3) + 8 * (r >> 2) + 4 * hi;
                float xc = (float)((r < 4) ? xq0[r & 3] : xq1[r & 3]);
                float xn = xc + (upd ? acc3[r] : 0.f);
                out[obase + (size_t)c * 36864] = xn;
                if (hi == 0 && r == 3)
                    alpha_out[(((size_t)bb) * 192 + h0 + prow) * 192 + w0 + pcol] = xn;
            }
        }

        // ---- write prefetched next halo into the other buffer ----
        if (have_next)
            halo_store(&s.halo[(it + 1) & 1][0][0][0], tid, pfv);
        __syncthreads();
    }
}

__global__ __launch_bounds__(256) void ca_mask(
    const float* __restrict__ x,
    const float* __restrict__ alpha_new,
    float* __restrict__ out)
{
    int pix = blockIdx.x * 256 + threadIdx.x;   // exactly 16*192*192 threads
    int ww = pix % 192; int t = pix / 192;
    int hh = t % 192;   int bb = t / 192;
    float pre = -1e30f, post = -1e30f;
#pragma unroll
    for (int di = -1; di <= 1; ++di) {
        int nh = hh + di;
        if (nh < 0 || nh >= 192) continue;
#pragma unroll
        for (int dj = -1; dj <= 1; ++dj) {
            int nw = ww + dj;
            if (nw < 0 || nw >= 192) continue;
            pre  = fmaxf(pre,  x[(((size_t)bb * 16 + 3) * 192 + nh) * 192 + nw]);
            post = fmaxf(post, alpha_new[(((size_t)bb) * 192 + nh) * 192 + nw]);
        }
    }
    bool alive = (pre > 0.1f) && (post > 0.1f);
    if (alive) return;                 // life==1 -> out already holds x_new
#pragma unroll
    for (int c = 0; c < 16; ++c) {
        out[(((size_t)bb * 16 + c) * 192 + hh) * 192 + ww] = 0.f;
    }
}

extern "C" void kernel_launch(void* const* d_in, const int* in_sizes, int n_in,
                              void* d_out, int out_size, void* d_ws, size_t ws_size,
                              hipStream_t stream) {
    const float* x    = (const float*)d_in[0];
    const float* w1   = (const float*)d_in[1];
    const float* b1   = (const float*)d_in[2];
    const float* w2   = (const float*)d_in[3];
    const float* b2   = (const float*)d_in[4];
    const float* w3   = (const float*)d_in[5];
    const float* b3   = (const float*)d_in[6];
    const float* fire = (const float*)d_in[7];
    float* out = (float*)d_out;

    _Float16* wh     = (_Float16*)d_ws;
    float* alpha_new = (float*)((char*)d_ws + ALPHA_BYTE_OFF);

    prep_weights<<<104, 256, 0, stream>>>(w1, w2, w3, wh);
    ca_main<<<NBLOCKS, 512, 0, stream>>>(x, b1, b2, b3, fire, wh, out, alpha_new);
    ca_mask<<<2304, 256, 0, stream>>>(x, alpha_new, out);
}